// Round 2
// baseline (481.265 us; speedup 1.0000x reference)
//
#include <hip/hip_runtime.h>
#include <math.h>

// -----------------------------------------------------------------------------
// DFSPH divergence-solve, block-aggregated binning + sort-based reduce.
//   pre:    per-particle 32B {p, r=m/aa, aa, aa^2/m | vx,vy,ax,ay}; zero cursors.
//   bin:    4096 edges/block, PURE STREAM. All 16 edges/thread loaded up front;
//           per-bucket rank via 2 LDS count arrays (A=first 2048, B=last 2048),
//           ONE cursor claim per (block,bucket) for the combined count -> mean
//           global run 8 records (128B) so 64B sectors are single-writer
//           (round-1 showed 224MB written for a 134MB payload = partial-sector
//           double eviction at run length 4). Two LDS sort rounds share the
//           claim; wave0 scans while waves 1-3 claim. Light barriers
//           (lgkmcnt-only + raw s_barrier) keep global loads/stores in flight
//           across phase boundaries. 16B record {jli=(j<<9)|li, gx, gy, gidx}.
//   reduce: double-buffered DMA stage + light barriers: tile T+1's
//           global_load_lds and the pre2[j] gathers stay outstanding across
//           hist -> scan -> scatter (round-1's __syncthreads drained vmcnt(0)
//           at every phase, serializing DMA/gather latency). Full syncthreads
//           only at loop top (DMA(cur) must have landed). In-LDS counting sort
//           per 512-record tile, then per-thread serial register accumulate.
//           spc=4 (was 8): halves partials traffic, 8 tiles/block pipeline.
//   fin:    sum nslice slices, alpha, write [N,5].
// Fallback (tiny ws): direct global float atomics.
// -----------------------------------------------------------------------------

#define PB        512
#define PB_SHIFT  9
#define SLICES    8
#define CSTRIDE   16      // ints per cursor -> 64B, one cacheline each
#define BIN_EPT   16      // edges per thread in bin (2 sort rounds of 8)
#define BIN_EDGES (256 * BIN_EPT)   // 4096
#define TILE      512     // records staged per reduce tile (8 KB per buffer)

typedef float v2f __attribute__((ext_vector_type(2)));

__device__ __forceinline__ void gload_lds16(const float4* g, float4* l) {
    __builtin_amdgcn_global_load_lds(
        (const __attribute__((address_space(1))) void*)g,
        (__attribute__((address_space(3))) void*)l, 16, 0, 0);
}

// LDS-only barrier: orders DS ops across the block WITHOUT draining vmcnt,
// so global loads / global_load_lds / stores stay in flight across phases.
__device__ __forceinline__ void ldsbar() {
    asm volatile("s_waitcnt lgkmcnt(0)" ::: "memory");
    __builtin_amdgcn_s_barrier();
    asm volatile("" ::: "memory");
}

static inline size_t align256(size_t x) { return (x + 255) & ~(size_t)255; }

__global__ __launch_bounds__(256) void pre_kernel(
    const float*  __restrict__ area,
    const float*  __restrict__ actualArea,
    const float*  __restrict__ restDensity,
    const float*  __restrict__ density,
    const float*  __restrict__ pressure2,
    const float2* __restrict__ vel,
    const float2* __restrict__ accel,
    float4* __restrict__ pre2,
    int*    __restrict__ cursor, int ncursor,
    float*  __restrict__ accz, int nacc,
    int n) {
    int t = blockIdx.x * blockDim.x + threadIdx.x;
    if (t < ncursor) cursor[t] = 0;
    for (int k = t; k < nacc; k += gridDim.x * blockDim.x) accz[k] = 0.f;
    if (t >= n) return;
    float m  = area[t] * restDensity[t];
    float dr = density[t] * restDensity[t];
    float p  = pressure2[t] / (dr * dr);
    float aa = actualArea[t];
    float2 v  = vel[t];
    float2 ac = accel[t];
    pre2[2 * (size_t)t]     = make_float4(p, m / aa, aa, aa * aa / m);
    pre2[2 * (size_t)t + 1] = make_float4(v.x, v.y, ac.x, ac.y);
}

__global__ __launch_bounds__(256) void bin_kernel(
    const int*    __restrict__ nbr,
    const float*  __restrict__ rad,
    const float2* __restrict__ dirs,
    const float*  __restrict__ supp,
    int*          __restrict__ cursor,
    float4*       __restrict__ pay,
    int cap, int nb, int estart, int eend, int E) {
    __shared__ float4 srec[2048];        // 32 KB bucket-sorted 16B records
    __shared__ int lcntA[512];           //  2 KB counts, round A
    __shared__ int lcntB[512];           //  2 KB counts, round B
    __shared__ int lclaim[512];          //  2 KB claimed global base (A+B)
    __shared__ int lstartA[512];         //  2 KB exclusive scan of A
    __shared__ int lstartB[512];         //  2 KB exclusive scan of B
    int tid = threadIdx.x;
    for (int k = tid; k < 512; k += 256) { lcntA[k] = 0; lcntB[k] = 0; }
    ldsbar();
    int eb = estart + blockIdx.x * BIN_EDGES + tid;

    // phase 1: stream ALL 16 edges/thread into registers, rank per bucket.
    // k<8 -> sort round A, k>=8 -> round B (LDS srec holds 2048 at a time).
    int jj[BIN_EPT]; float qq[BIN_EPT]; v2f dd[BIN_EPT]; int pk[BIN_EPT];
#pragma unroll
    for (int k = 0; k < BIN_EPT; ++k) {
        int e = eb + k * 256;
        pk[k] = -1; jj[k] = 0; qq[k] = 0.f; dd[k] = (v2f){0.f, 0.f};
        if (e < eend) {
            jj[k] = __builtin_nontemporal_load(nbr + E + e);
            qq[k] = __builtin_nontemporal_load(rad + e);
            dd[k] = __builtin_nontemporal_load((const v2f*)dirs + e);
            int i = __builtin_nontemporal_load(nbr + e);
            int b = i >> PB_SHIFT;
            int r = (k < 8) ? atomicAdd(&lcntA[b], 1) : atomicAdd(&lcntB[b], 1);
            pk[k] = (b << 22) | ((i & (PB - 1)) << 12) | r;
        }
    }
    ldsbar();
    // waves 1-3: one global cursor claim per (block,bucket) for A+B combined;
    // wave 0: exclusive scans of A and B counts (runs concurrently)
    if (tid >= 64) {
        for (int k = tid - 64; k < nb; k += 192) {
            int c = lcntA[k] + lcntB[k];
            lclaim[k] = c ? atomicAdd(&cursor[(size_t)k * CSTRIDE], c) : 0;
        }
    } else {
        int runA = 0, runB = 0;
        for (int c = 0; c < 8; ++c) {
            int oA = lcntA[c * 64 + tid]; int vA = oA;
            int oB = lcntB[c * 64 + tid]; int vB = oB;
#pragma unroll
            for (int off = 1; off < 64; off <<= 1) {
                int uA = __shfl_up(vA, off, 64);
                int uB = __shfl_up(vB, off, 64);
                if (tid >= off) { vA += uA; vB += uB; }
            }
            lstartA[c * 64 + tid] = runA + vA - oA;
            lstartB[c * 64 + tid] = runB + vB - oB;
            runA += __shfl(vA, 63, 64);
            runB += __shfl(vB, 63, 64);
        }
    }
    ldsbar();

    float h  = supp[0];
    float kc = 20.0f * (7.0f / 3.14159265358979323846f) / (h * h * h);

    // phase 2A: compute gradient, scatter 16B record into bucket-sorted LDS
#pragma unroll
    for (int k = 0; k < 8; ++k) {
        if (pk[k] < 0) continue;
        int b  = pk[k] >> 22;
        int li = (pk[k] >> 12) & (PB - 1);
        int r  = pk[k] & 4095;
        float  q = qq[k];
        v2f    d = dd[k];
        float om  = 1.0f - q;
        float mag = kc * q * om * om * om;
        float gx = -d.x * mag;
        float gy = -d.y * mag;
        int jli  = (jj[k] << 9) | li;
        int g    = lclaim[b] + r;
        int gi   = (g < cap) ? (b * cap + g) : -1;  // 8-sigma drop margin
        srec[lstartA[b] + r] = make_float4(__int_as_float(jli), gx, gy,
                                           __int_as_float(gi));
    }
    ldsbar();
    // writeout A: wave-linear -> bucket runs contiguous, coalesced sectors
    {
        int total = lstartA[511] + lcntA[511];
        for (int t = tid; t < total; t += 256) {
            float4 rec = srec[t];
            int gi = __float_as_int(rec.w);
            if (gi >= 0) pay[gi] = make_float4(rec.x, rec.y, rec.z, 0.f);
        }
    }
    ldsbar();   // srec reads done (stores may still be in flight: fine)
    // phase 2B: second 2048 records; global base continues after A's count
#pragma unroll
    for (int k = 8; k < BIN_EPT; ++k) {
        if (pk[k] < 0) continue;
        int b  = pk[k] >> 22;
        int li = (pk[k] >> 12) & (PB - 1);
        int r  = pk[k] & 4095;
        float  q = qq[k];
        v2f    d = dd[k];
        float om  = 1.0f - q;
        float mag = kc * q * om * om * om;
        float gx = -d.x * mag;
        float gy = -d.y * mag;
        int jli  = (jj[k] << 9) | li;
        int g    = lclaim[b] + lcntA[b] + r;
        int gi   = (g < cap) ? (b * cap + g) : -1;
        srec[lstartB[b] + r] = make_float4(__int_as_float(jli), gx, gy,
                                           __int_as_float(gi));
    }
    ldsbar();
    {
        int total = lstartB[511] + lcntB[511];
        for (int t = tid; t < total; t += 256) {
            float4 rec = srec[t];
            int gi = __float_as_int(rec.w);
            if (gi >= 0) pay[gi] = make_float4(rec.x, rec.y, rec.z, 0.f);
        }
    }
}

__global__ __launch_bounds__(256) void reduce_kernel(
    const float4* __restrict__ pay,
    const int*    __restrict__ cursor, int cap,
    const float4* __restrict__ pre2,
    const float*  __restrict__ dtp,
    float*        __restrict__ partials,
    int spc, int soff, int n) {
    __shared__ float4 stage[2][TILE];    // 16 KB double-buffered raw records
    __shared__ float4 sorted[TILE * 2];  // 16 KB expanded 32B records
    __shared__ int    lhist[PB];         //  2 KB counts
    __shared__ int    lofs[PB];          //  2 KB exclusive offsets -> cursors
    int b   = blockIdx.x / spc;
    int s   = blockIdx.x % spc;
    int tid = threadIdx.x;

    // this thread owns particles p0 = base+tid and p1 = base+tid+256
    int p0 = (b << PB_SHIFT) + tid;
    int p1 = p0 + 256;
    float pi0 = (p0 < n) ? pre2[2 * (size_t)p0].x : 0.f;
    float pi1 = (p1 < n) ? pre2[2 * (size_t)p1].x : 0.f;
    float a0[7] = {0.f, 0.f, 0.f, 0.f, 0.f, 0.f, 0.f};
    float a1[7] = {0.f, 0.f, 0.f, 0.f, 0.f, 0.f, 0.f};
    float dt  = dtp[0];
    float dt2 = dt * dt;

    int cnt = cursor[(size_t)b * CSTRIDE];
    if (cnt > cap) cnt = cap;
    int lo = (int)((long long)cnt * s / spc);
    int hi = (int)((long long)cnt * (s + 1) / spc);
    size_t base = (size_t)b * cap;

    // prologue: DMA first tile into buffer 0
    if (lo < hi) {
#pragma unroll
        for (int si = 0; si < 2; ++si) {
            int fl  = (si << 8) + tid;
            int rec = lo + fl;
            size_t g = (rec < hi) ? (base + rec) : base;
            gload_lds16(pay + g, &stage[0][fl]);
        }
    }
    int cur = 0;
    for (int T = lo; T < hi; T += TILE) {
        __syncthreads();   // FULL drain: DMA(cur) landed; prev gather done
        lhist[tid] = 0; lhist[tid + 256] = 0;
        float4 r0 = stage[cur][tid];
        float4 r1 = stage[cur][tid + 256];
        bool v0 = (T + tid) < hi;
        bool v1 = (T + tid + 256) < hi;
        int jli0 = __float_as_int(r0.x);
        int jli1 = __float_as_int(r1.x);
        int li0 = jli0 & (PB - 1);
        int li1 = jli1 & (PB - 1);
        size_t j0 = (size_t)(v0 ? (jli0 >> 9) : 0);
        size_t j1 = (size_t)(v1 ? (jli1 >> 9) : 0);
        // issue gathers (used at scatter; stay in flight across light barriers)
        float4 ja0 = pre2[2 * j0], jb0 = pre2[2 * j0 + 1];
        float4 ja1 = pre2[2 * j1], jb1 = pre2[2 * j1 + 1];
        // issue next tile's DMA into the other buffer (in flight until next
        // loop-top __syncthreads)
        int Tn = T + TILE;
        if (Tn < hi) {
#pragma unroll
            for (int si = 0; si < 2; ++si) {
                int fl  = (si << 8) + tid;
                int rec = Tn + fl;
                size_t g = (rec < hi) ? (base + rec) : base;
                gload_lds16(pay + g, &stage[cur ^ 1][fl]);
            }
        }
        ldsbar();          // hist zeros visible; DMA/gathers NOT drained
        if (v0) atomicAdd(&lhist[li0], 1);
        if (v1) atomicAdd(&lhist[li1], 1);
        ldsbar();
        // exclusive prefix scan of 512 counts by wave 0
        if (tid < 64) {
            int running = 0;
            for (int c = 0; c < 8; ++c) {
                int orig = lhist[c * 64 + tid];
                int v = orig;
#pragma unroll
                for (int off = 1; off < 64; off <<= 1) {
                    int u = __shfl_up(v, off, 64);
                    if (tid >= off) v += u;
                }
                lofs[c * 64 + tid] = running + v - orig;
                running += __shfl(v, 63, 64);
            }
        }
        ldsbar();
        // scatter: expand to full computed record in particle-sorted order
        if (v0) {
            int slot = atomicAdd(&lofs[li0], 1);
            float c0 = ja0.z * r0.y;                        // aa*gx
            float c1 = ja0.z * r0.z;                        // aa*gy
            float c2 = ja0.w * (r0.y * r0.y + r0.z * r0.z); // aa2m*g2
            float q5 = dt  * (jb0.x * c0 + jb0.y * c1);     // dt*aa*(vj.g)
            float q6 = dt2 * (jb0.z * c0 + jb0.w * c1);     // dt^2*aa*(aj.g)
            sorted[2 * slot]     = make_float4(c0, c1, c2, ja0.y);
            sorted[2 * slot + 1] = make_float4(ja0.x, q5, q6, 0.f);
        }
        if (v1) {
            int slot = atomicAdd(&lofs[li1], 1);
            float c0 = ja1.z * r1.y;
            float c1 = ja1.z * r1.z;
            float c2 = ja1.w * (r1.y * r1.y + r1.z * r1.z);
            float q5 = dt  * (jb1.x * c0 + jb1.y * c1);
            float q6 = dt2 * (jb1.z * c0 + jb1.w * c1);
            sorted[2 * slot]     = make_float4(c0, c1, c2, ja1.y);
            sorted[2 * slot + 1] = make_float4(ja1.x, q5, q6, 0.f);
        }
        ldsbar();
        // register gather: contiguous segment per particle, NO atomics
        {
            int end0 = lofs[tid];
            for (int r = end0 - lhist[tid]; r < end0; ++r) {
                float4 e0 = sorted[2 * r];
                float4 e1 = sorted[2 * r + 1];
                float rc = -(pi0 + e1.x) * e0.w;
                a0[0] += e0.x; a0[1] += e0.y; a0[2] += e0.z;
                a0[3] += rc * e0.x; a0[4] += rc * e0.y;
                a0[5] += e1.y; a0[6] += e1.z;
            }
            int end1 = lofs[tid + 256];
            for (int r = end1 - lhist[tid + 256]; r < end1; ++r) {
                float4 e0 = sorted[2 * r];
                float4 e1 = sorted[2 * r + 1];
                float rc = -(pi1 + e1.x) * e0.w;
                a1[0] += e0.x; a1[1] += e0.y; a1[2] += e0.z;
                a1[3] += rc * e0.x; a1[4] += rc * e0.y;
                a1[5] += e1.y; a1[6] += e1.z;
            }
        }
        cur ^= 1;
        // loop-top __syncthreads protects lhist/lofs/sorted + drains DMA(cur)
    }

    // epilogue: apply linear i-side corrections, write slice from registers
    float* dst = partials + ((size_t)b * SLICES + soff + s) * (PB * 7);
    {
        float4 va = (p0 < n) ? pre2[2 * (size_t)p0 + 1]
                             : make_float4(0.f, 0.f, 0.f, 0.f);
        float src = a0[5] - dt  * (va.x * a0[0] + va.y * a0[1]);
        float ker = dt2 * (va.z * a0[0] + va.w * a0[1]) - a0[6];
        float* d = dst + (size_t)tid * 7;
        d[0] = a0[0]; d[1] = a0[1]; d[2] = a0[2]; d[3] = a0[3]; d[4] = a0[4];
        d[5] = src;   d[6] = ker;
    }
    {
        float4 va = (p1 < n) ? pre2[2 * (size_t)p1 + 1]
                             : make_float4(0.f, 0.f, 0.f, 0.f);
        float src = a1[5] - dt  * (va.x * a1[0] + va.y * a1[1]);
        float ker = dt2 * (va.z * a1[0] + va.w * a1[1]) - a1[6];
        float* d = dst + (size_t)(tid + 256) * 7;
        d[0] = a1[0]; d[1] = a1[1]; d[2] = a1[2]; d[3] = a1[3]; d[4] = a1[4];
        d[5] = src;   d[6] = ker;
    }
}

// ---- fallback: direct global float atomics ----
__global__ void edge_kernel(const int* __restrict__ nbr,
                            const float* __restrict__ rad,
                            const float2* __restrict__ dirs,
                            const float4* __restrict__ pre2,
                            const float* __restrict__ supp,
                            const float* __restrict__ dtp,
                            float* __restrict__ acc, int E) {
    int e = blockIdx.x * blockDim.x + threadIdx.x;
    if (e >= E) return;
    float h = supp[0], dt = dtp[0];
    float kc = 20.0f * (7.0f / 3.14159265358979323846f) / (h * h * h);
    int i = nbr[e];
    int j = nbr[E + e];
    float  q = rad[e];
    float2 d = dirs[e];
    float om  = 1.0f - q;
    float mag = kc * q * om * om * om;
    float gx = -d.x * mag;
    float gy = -d.y * mag;
    float g2 = gx * gx + gy * gy;
    float4 ja = pre2[2 * (size_t)j];      // {p, r, aa, aa2m}
    float4 jb = pre2[2 * (size_t)j + 1];
    float4 ia = pre2[2 * (size_t)i];
    float4 ib = pre2[2 * (size_t)i + 1];
    float aaj = ja.z;
    float m   = ja.y * aaj;
    float pp  = -m * (ia.x + ja.x);
    float vdotg = (ib.x - jb.x) * gx + (ib.y - jb.y) * gy;
    float adotg = (ib.z - jb.z) * gx + (ib.w - jb.w) * gy;
    float* base = acc + (size_t)i * 8;
    atomicAdd(base + 0, aaj * gx);
    atomicAdd(base + 1, aaj * gy);
    atomicAdd(base + 2, ja.w * g2);
    atomicAdd(base + 3, pp * gx);
    atomicAdd(base + 4, pp * gy);
    atomicAdd(base + 5, -dt * aaj * vdotg);
    atomicAdd(base + 6, dt * dt * aaj * adotg);
}

__global__ __launch_bounds__(256) void fin_kernel(
    const float* __restrict__ area,
    const float* __restrict__ actualArea,
    const float* __restrict__ restDensity,
    const float* __restrict__ dtp,
    const float* __restrict__ data, int mode, int nslice,
    float* __restrict__ out, int n) {
    int t = blockIdx.x * blockDim.x + threadIdx.x;
    if (t >= n) return;
    float s0 = 0, s1 = 0, s2 = 0, s3 = 0, s4 = 0, s5 = 0, s6 = 0;
    if (mode == 0) {
        const float* base = data + ((size_t)(t >> PB_SHIFT) * SLICES) * (PB * 7)
                                 + (size_t)(t & (PB - 1)) * 7;
        for (int s = 0; s < nslice; ++s) {
            const float* p = base + (size_t)s * (PB * 7);
            s0 += p[0]; s1 += p[1]; s2 += p[2]; s3 += p[3];
            s4 += p[4]; s5 += p[5]; s6 += p[6];
        }
    } else {
        const float* a = data + (size_t)t * 8;
        s0 = a[0]; s1 = a[1]; s2 = a[2]; s3 = a[3];
        s4 = a[4]; s5 = a[5]; s6 = a[6];
    }
    float dt   = dtp[0];
    float fac  = -dt * dt * actualArea[t];
    float mass = area[t] * restDensity[t];
    float alpha = fac / mass * (s0 * s0 + s1 * s1) + fac * s2;
    float* o = out + (size_t)t * 5;
    o[0] = alpha;
    o[1] = s3;
    o[2] = s4;
    o[3] = s5;
    o[4] = s6;
}

extern "C" void kernel_launch(void* const* d_in, const int* in_sizes, int n_in,
                              void* d_out, int out_size, void* d_ws, size_t ws_size,
                              hipStream_t stream) {
    const float* area        = (const float*)d_in[0];
    const float* actualArea  = (const float*)d_in[1];
    const float* restDensity = (const float*)d_in[2];
    const float* density     = (const float*)d_in[3];
    const float* pressure2   = (const float*)d_in[4];
    const float2* vel        = (const float2*)d_in[5];
    const float2* accel      = (const float2*)d_in[6];
    const float* rad         = (const float*)d_in[7];
    const float2* dirs       = (const float2*)d_in[8];
    const int*   nbr         = (const int*)d_in[9];
    const float* supp        = (const float*)d_in[10];
    const float* dtp         = (const float*)d_in[11];
    float* out = (float*)d_out;

    int N = in_sizes[0];
    int E = in_sizes[7];
    int nb = (N + PB - 1) >> PB_SHIFT;   // 512 for N=262144

    size_t sz_cur   = (size_t)nb * CSTRIDE * 8 * sizeof(int);
    size_t off_pre  = align256(sz_cur);
    size_t sz_pre   = (size_t)N * 8 * sizeof(float);
    size_t off_part = align256(off_pre + sz_pre);
    size_t sz_part  = (size_t)nb * SLICES * PB * 7 * sizeof(float);
    size_t off_pay  = align256(off_part + sz_part);

    int* cursor     = (int*)d_ws;
    float4* pre2    = (float4*)((char*)d_ws + off_pre);
    float* partials = (float*)((char*)d_ws + off_part);

    // pick chunking so payload fits (one 16B record/edge, bucket-grouped)
    int nchunk = 0, cap = 0;
    if (nb <= 512 && ws_size > off_pay) {
        for (int c = 1; c <= 8; c *= 2) {
            long long Ec = (E + c - 1) / c;
            double mean = (double)Ec / (double)nb;
            long long need = (long long)(mean + 8.0 * sqrt(mean) + 128.0);
            need = (need + 63) & ~63ll;
            if (off_pay + (size_t)nb * need * 16 <= ws_size) {
                nchunk = c; cap = (int)need; break;
            }
        }
    }

    int bs = 256;
    int grid_n = (N + bs - 1) / bs;
    if (nchunk > 0) {
        float4* pay = (float4*)((char*)d_ws + off_pay);
        int ncursor = nb * CSTRIDE * nchunk;
        pre_kernel<<<grid_n, bs, 0, stream>>>(
            area, actualArea, restDensity, density, pressure2, vel, accel,
            pre2, cursor, ncursor, (float*)nullptr, 0, N);
        int spc = 4 / nchunk; if (spc < 1) spc = 1;
        int nslice = spc * nchunk;
        int Ec  = (E + nchunk - 1) / nchunk;
        for (int c = 0; c < nchunk; ++c) {
            int es = c * Ec;
            int ee = es + Ec; if (ee > E) ee = E;
            if (es >= ee) break;
            int* curC = cursor + (size_t)c * nb * CSTRIDE;
            int nblk = (ee - es + BIN_EDGES - 1) / BIN_EDGES;
            bin_kernel<<<nblk, bs, 0, stream>>>(
                nbr, rad, dirs, supp, curC, pay, cap, nb, es, ee, E);
            reduce_kernel<<<nb * spc, bs, 0, stream>>>(
                pay, curC, cap, pre2, dtp, partials, spc, c * spc, N);
        }
        fin_kernel<<<grid_n, bs, 0, stream>>>(
            area, actualArea, restDensity, dtp, partials, 0, nslice, out, N);
    } else {
        float* acc = partials;  // [N,8] at off_part
        pre_kernel<<<grid_n, bs, 0, stream>>>(
            area, actualArea, restDensity, density, pressure2, vel, accel,
            pre2, cursor, 0, acc, N * 8, N);
        edge_kernel<<<(E + bs - 1) / bs, bs, 0, stream>>>(
            nbr, rad, dirs, pre2, supp, dtp, acc, E);
        fin_kernel<<<grid_n, bs, 0, stream>>>(
            area, actualArea, restDensity, dtp, acc, 1,0, out, N);
    }
}

// Round 3
// 397.876 us; speedup vs baseline: 1.2096x; 1.2096x over previous
//
#include <hip/hip_runtime.h>
#include <math.h>

// -----------------------------------------------------------------------------
// DFSPH divergence-solve, block-aggregated binning + sort-based reduce.
//   pre:    per-particle 32B {p, r=m/aa, aa, aa^2/m | vx,vy,ax,ay}; zero cursors.
//   bin:    2048 edges/block (round-1 structure, 64 VGPR), PURE STREAM.
//           Payload is split into NR=8 pseudo-XCD regions keyed by blockIdx&7:
//           adjacent cursor claims within a region come from blocks on the
//           same XCD (round-robin dispatch), so partial 64B sectors merge in
//           that XCD's L2 instead of double-evicting to HBM (round-1/2 showed
//           224MB written for a 101-134MB payload). 12B record {jli,gx,gy}
//           written as a contiguous DWORD stream from an interleaved LDS sort
//           buffer -> fully coalesced dword stores.
//   reduce: NO LDS stage: each thread register-loads 4 consecutive records
//           (3x dwordx4), double-buffered across tiles; pre2[j] gathers issued
//           early (L2/L3-resident), latency hidden under hist+scan. Counting
//           sort per TILE=1024 records into 7 SoA b32 arrays (random-slot b32
//           = ~2-way bank alias = free; the old AoS b128 scatter/gather was
//           ~8-way). rc precomputed at scatter via LDS ptab of pi -> gather is
//           7 pure-sum b32 adds per record. All barriers lgkmcnt-only.
//   fin:    sum SLICES=8 slices (one per region), alpha, write [N,5].
// Fallback (tiny ws): direct global float atomics.
// -----------------------------------------------------------------------------

#define PB        512
#define PB_SHIFT  9
#define SLICES    8
#define CSTRIDE   16      // ints per cursor -> 64B, one cacheline each
#define NR        8       // payload regions (pseudo-XCD via blockIdx&7)
#define BIN_EDGES 2048
#define TILE      1024    // records per reduce sort round

typedef float v2f __attribute__((ext_vector_type(2)));

// LDS-only barrier: orders DS ops across the block WITHOUT draining vmcnt,
// so global loads/stores stay in flight across phases.
__device__ __forceinline__ void ldsbar() {
    asm volatile("s_waitcnt lgkmcnt(0)" ::: "memory");
    __builtin_amdgcn_s_barrier();
    asm volatile("" ::: "memory");
}

static inline size_t align256(size_t x) { return (x + 255) & ~(size_t)255; }

__global__ __launch_bounds__(256) void pre_kernel(
    const float*  __restrict__ area,
    const float*  __restrict__ actualArea,
    const float*  __restrict__ restDensity,
    const float*  __restrict__ density,
    const float*  __restrict__ pressure2,
    const float2* __restrict__ vel,
    const float2* __restrict__ accel,
    float4* __restrict__ pre2,
    int*    __restrict__ cursor, int ncursor,
    float*  __restrict__ accz, int nacc,
    int n) {
    int t = blockIdx.x * blockDim.x + threadIdx.x;
    int stride = gridDim.x * blockDim.x;
    for (int k = t; k < ncursor; k += stride) cursor[k] = 0;
    for (int k = t; k < nacc; k += stride) accz[k] = 0.f;
    if (t >= n) return;
    float m  = area[t] * restDensity[t];
    float dr = density[t] * restDensity[t];
    float p  = pressure2[t] / (dr * dr);
    float aa = actualArea[t];
    float2 v  = vel[t];
    float2 ac = accel[t];
    pre2[2 * (size_t)t]     = make_float4(p, m / aa, aa, aa * aa / m);
    pre2[2 * (size_t)t + 1] = make_float4(v.x, v.y, ac.x, ac.y);
}

__global__ __launch_bounds__(256) void bin_kernel(
    const int*    __restrict__ nbr,
    const float*  __restrict__ rad,
    const float2* __restrict__ dirs,
    const float*  __restrict__ supp,
    int*          __restrict__ cursor,
    unsigned int* __restrict__ pay32,
    int cap, int nb, int estart, int eend, int E) {
    __shared__ float s3[BIN_EDGES * 3];  // 24 KB interleaved {jli,gx,gy}
    __shared__ int   sD[BIN_EDGES];      //  8 KB per-record global dword base
    __shared__ int lcount[512];          //  2 KB per-bucket counts
    __shared__ int lclaim[512];          //  2 KB claimed global record base
    __shared__ int lstart[512];          //  2 KB exclusive scan (LDS slot)
    int tid = threadIdx.x;
    int x   = blockIdx.x & (NR - 1);     // pseudo-XCD region
    for (int k = tid; k < 512; k += 256) lcount[k] = 0;
    ldsbar();
    int e0 = estart + blockIdx.x * BIN_EDGES + tid;

    // phase 1: stream 8 edges/thread into registers, rank per bucket
    int jj[8]; float qq[8]; v2f dd[8]; int pk[8];
#pragma unroll
    for (int k = 0; k < 8; ++k) {
        int e = e0 + k * 256;
        pk[k] = -1; jj[k] = 0; qq[k] = 0.f; dd[k] = (v2f){0.f, 0.f};
        if (e < eend) {
            jj[k] = __builtin_nontemporal_load(nbr + E + e);
            qq[k] = __builtin_nontemporal_load(rad + e);
            dd[k] = __builtin_nontemporal_load((const v2f*)dirs + e);
            int i = __builtin_nontemporal_load(nbr + e);
            int b = i >> PB_SHIFT;
            int r = atomicAdd(&lcount[b], 1);
            pk[k] = (b << 21) | ((i & (PB - 1)) << 12) | r;
        }
    }
    ldsbar();
    // waves 1-3: one cursor claim per (block,bucket) in region x;
    // wave 0: exclusive scan of counts (concurrent)
    if (tid >= 64) {
        for (int k = tid - 64; k < nb; k += 192) {
            int c = lcount[k];
            lclaim[k] = c ? atomicAdd(&cursor[(size_t)(k * NR + x) * CSTRIDE], c) : 0;
        }
    } else {
        int running = 0;
        for (int c = 0; c < 8; ++c) {
            int orig = lcount[c * 64 + tid];
            int v = orig;
#pragma unroll
            for (int off = 1; off < 64; off <<= 1) {
                int u = __shfl_up(v, off, 64);
                if (tid >= off) v += u;
            }
            lstart[c * 64 + tid] = running + v - orig;
            running += __shfl(v, 63, 64);
        }
    }
    ldsbar();

    float h  = supp[0];
    float kc = 20.0f * (7.0f / 3.14159265358979323846f) / (h * h * h);
    int cap3  = cap * 3;       // dwords per region
    int cap24 = cap * 3 * NR;  // dwords per bucket

    // phase 2: compute gradient, scatter 12B record into bucket-sorted LDS
#pragma unroll
    for (int k = 0; k < 8; ++k) {
        if (pk[k] < 0) continue;
        int b  = pk[k] >> 21;
        int li = (pk[k] >> 12) & (PB - 1);
        int r  = pk[k] & 2047;
        float  q = qq[k];
        v2f    d = dd[k];
        float om  = 1.0f - q;
        float mag = kc * q * om * om * om;
        float gx = -d.x * mag;
        float gy = -d.y * mag;
        int slot = lstart[b] + r;
        s3[slot * 3 + 0] = __int_as_float((jj[k] << PB_SHIFT) | li);
        s3[slot * 3 + 1] = gx;
        s3[slot * 3 + 2] = gy;
        int g = lclaim[b] + r;
        sD[slot] = (g < cap) ? (b * cap24 + x * cap3 + g * 3) : -1;
    }
    ldsbar();
    // writeout: dword-linear over the sorted LDS stream -> contiguous dword
    // stores within each bucket run; same-region neighbors share an L2.
    int total3 = (lstart[511] + lcount[511]) * 3;
    for (int dwi = tid; dwi < total3; dwi += 256) {
        int rec = dwi / 3;
        int f   = dwi - rec * 3;
        int gd  = sD[rec];
        if (gd >= 0) pay32[gd + f] = __float_as_uint(s3[dwi]);
    }
}

__global__ __launch_bounds__(256) void reduce_kernel(
    const unsigned int* __restrict__ pay32,
    const int*    __restrict__ cursor, int cap,
    const float4* __restrict__ pre2,
    const float*  __restrict__ dtp,
    float*        __restrict__ partials,
    int accum, int n) {
    __shared__ float s7[7][TILE];        // 28 KB SoA expanded records
    __shared__ int   lhist[PB];          //  2 KB counts
    __shared__ int   lofs[PB];           //  2 KB offsets -> cursors
    __shared__ float ptab[PB];           //  2 KB per-particle p
    int b   = blockIdx.x >> 3;
    int s   = blockIdx.x & (NR - 1);
    int tid = threadIdx.x;

    int p0 = (b << PB_SHIFT) + tid;
    int p1 = p0 + 256;
    float pi0 = (p0 < n) ? pre2[2 * (size_t)p0].x : 0.f;
    float pi1 = (p1 < n) ? pre2[2 * (size_t)p1].x : 0.f;
    ptab[tid] = pi0; ptab[tid + 256] = pi1;
    float a0[7] = {0.f, 0.f, 0.f, 0.f, 0.f, 0.f, 0.f};
    float a1[7] = {0.f, 0.f, 0.f, 0.f, 0.f, 0.f, 0.f};
    float dt  = dtp[0];
    float dt2 = dt * dt;

    int cnt = cursor[(size_t)(b * NR + s) * CSTRIDE];
    if (cnt > cap) cnt = cap;
    size_t RB = (size_t)(b * NR + s) * cap * 3;  // dword base of this region
    int r0 = tid * 4;                            // this thread's 4 records

    float4 c0v, c1v, c2v, n0v, n1v, n2v;
    // prologue: load tile 0 (3x dwordx4 = 4 records of 12B)
    if (cnt > 0) {
        int rb = r0;
        int rc_ = (rb + 4 <= cap) ? rb : (cap - 4);
        const float4* g = (const float4*)(pay32 + RB + (size_t)rc_ * 3);
        c0v = g[0]; c1v = g[1]; c2v = g[2];
    }
    for (int T = 0; T < cnt; T += TILE) {
        lhist[tid] = 0; lhist[tid + 256] = 0;
        // issue next tile's loads (stay in flight across the whole pipeline)
        if (T + TILE < cnt) {
            int rb = T + TILE + r0;
            int rc_ = (rb + 4 <= cap) ? rb : (cap - 4);
            const float4* g = (const float4*)(pay32 + RB + (size_t)rc_ * 3);
            n0v = g[0]; n1v = g[1]; n2v = g[2];
        }
        // extract 4 records; issue pre2[j] gathers EARLY
        int rb = T + r0;
        bool v0 = rb < cnt, v1 = rb + 1 < cnt, v2 = rb + 2 < cnt, v3 = rb + 3 < cnt;
        int jli0 = __float_as_int(c0v.x); float gx0 = c0v.y, gy0 = c0v.z;
        int jli1 = __float_as_int(c0v.w); float gx1 = c1v.x, gy1 = c1v.y;
        int jli2 = __float_as_int(c1v.z); float gx2 = c1v.w, gy2 = c2v.x;
        int jli3 = __float_as_int(c2v.y); float gx3 = c2v.z, gy3 = c2v.w;
        int li0 = jli0 & (PB - 1), li1 = jli1 & (PB - 1);
        int li2 = jli2 & (PB - 1), li3 = jli3 & (PB - 1);
        size_t j0 = v0 ? (size_t)(jli0 >> PB_SHIFT) : 0;
        size_t j1 = v1 ? (size_t)(jli1 >> PB_SHIFT) : 0;
        size_t j2 = v2 ? (size_t)(jli2 >> PB_SHIFT) : 0;
        size_t j3 = v3 ? (size_t)(jli3 >> PB_SHIFT) : 0;
        float4 ja0 = pre2[2 * j0], jb0 = pre2[2 * j0 + 1];
        float4 ja1 = pre2[2 * j1], jb1 = pre2[2 * j1 + 1];
        float4 ja2 = pre2[2 * j2], jb2 = pre2[2 * j2 + 1];
        float4 ja3 = pre2[2 * j3], jb3 = pre2[2 * j3 + 1];
        ldsbar();          // hist zeros + ptab visible
        if (v0) atomicAdd(&lhist[li0], 1);
        if (v1) atomicAdd(&lhist[li1], 1);
        if (v2) atomicAdd(&lhist[li2], 1);
        if (v3) atomicAdd(&lhist[li3], 1);
        ldsbar();
        // exclusive prefix scan of 512 counts by wave 0
        if (tid < 64) {
            int running = 0;
            for (int c = 0; c < 8; ++c) {
                int orig = lhist[c * 64 + tid];
                int v = orig;
#pragma unroll
                for (int off = 1; off < 64; off <<= 1) {
                    int u = __shfl_up(v, off, 64);
                    if (tid >= off) v += u;
                }
                lofs[c * 64 + tid] = running + v - orig;
                running += __shfl(v, 63, 64);
            }
        }
        ldsbar();
        // scatter: expand + write 7 SoA b32 arrays in particle-sorted order
#define SCAT(vv, li, jaa, jbb, gxx, gyy)                                     \
        if (vv) {                                                            \
            int sl = atomicAdd(&lofs[li], 1);                                \
            float C0 = jaa.z * gxx;                                          \
            float C1 = jaa.z * gyy;                                          \
            float C2 = jaa.w * (gxx * gxx + gyy * gyy);                      \
            float rc = -(ptab[li] + jaa.x) * jaa.y;                          \
            s7[0][sl] = C0;      s7[1][sl] = C1;      s7[2][sl] = C2;        \
            s7[3][sl] = rc * C0; s7[4][sl] = rc * C1;                        \
            s7[5][sl] = dt  * (jbb.x * C0 + jbb.y * C1);                     \
            s7[6][sl] = dt2 * (jbb.z * C0 + jbb.w * C1);                     \
        }
        SCAT(v0, li0, ja0, jb0, gx0, gy0)
        SCAT(v1, li1, ja1, jb1, gx1, gy1)
        SCAT(v2, li2, ja2, jb2, gx2, gy2)
        SCAT(v3, li3, ja3, jb3, gx3, gy3)
#undef SCAT
        ldsbar();
        // gather: contiguous segment per particle, pure-sum b32 reads
        {
            int e0 = lofs[tid], h0 = lhist[tid];
            for (int r = e0 - h0; r < e0; ++r) {
                a0[0] += s7[0][r]; a0[1] += s7[1][r]; a0[2] += s7[2][r];
                a0[3] += s7[3][r]; a0[4] += s7[4][r];
                a0[5] += s7[5][r]; a0[6] += s7[6][r];
            }
            int e1 = lofs[tid + 256], h1 = lhist[tid + 256];
            for (int r = e1 - h1; r < e1; ++r) {
                a1[0] += s7[0][r]; a1[1] += s7[1][r]; a1[2] += s7[2][r];
                a1[3] += s7[3][r]; a1[4] += s7[4][r];
                a1[5] += s7[5][r]; a1[6] += s7[6][r];
            }
        }
        ldsbar();          // gather done before next tile zeroes lhist
        c0v = n0v; c1v = n1v; c2v = n2v;
    }

    // epilogue: apply linear i-side corrections, write/accumulate slice
    float* dst = partials + ((size_t)b * SLICES + s) * (PB * 7);
    {
        float4 va = (p0 < n) ? pre2[2 * (size_t)p0 + 1]
                             : make_float4(0.f, 0.f, 0.f, 0.f);
        float src = a0[5] - dt  * (va.x * a0[0] + va.y * a0[1]);
        float ker = dt2 * (va.z * a0[0] + va.w * a0[1]) - a0[6];
        float* d = dst + (size_t)tid * 7;
        if (accum) {
            d[0] += a0[0]; d[1] += a0[1]; d[2] += a0[2]; d[3] += a0[3];
            d[4] += a0[4]; d[5] += src;   d[6] += ker;
        } else {
            d[0] = a0[0]; d[1] = a0[1]; d[2] = a0[2]; d[3] = a0[3];
            d[4] = a0[4]; d[5] = src;   d[6] = ker;
        }
    }
    {
        float4 va = (p1 < n) ? pre2[2 * (size_t)p1 + 1]
                             : make_float4(0.f, 0.f, 0.f, 0.f);
        float src = a1[5] - dt  * (va.x * a1[0] + va.y * a1[1]);
        float ker = dt2 * (va.z * a1[0] + va.w * a1[1]) - a1[6];
        float* d = dst + (size_t)(tid + 256) * 7;
        if (accum) {
            d[0] += a1[0]; d[1] += a1[1]; d[2] += a1[2]; d[3] += a1[3];
            d[4] += a1[4]; d[5] += src;   d[6] += ker;
        } else {
            d[0] = a1[0]; d[1] = a1[1]; d[2] = a1[2]; d[3] = a1[3];
            d[4] = a1[4]; d[5] = src;   d[6] = ker;
        }
    }
}

// ---- fallback: direct global float atomics ----
__global__ void edge_kernel(const int* __restrict__ nbr,
                            const float* __restrict__ rad,
                            const float2* __restrict__ dirs,
                            const float4* __restrict__ pre2,
                            const float* __restrict__ supp,
                            const float* __restrict__ dtp,
                            float* __restrict__ acc, int E) {
    int e = blockIdx.x * blockDim.x + threadIdx.x;
    if (e >= E) return;
    float h = supp[0], dt = dtp[0];
    float kc = 20.0f * (7.0f / 3.14159265358979323846f) / (h * h * h);
    int i = nbr[e];
    int j = nbr[E + e];
    float  q = rad[e];
    float2 d = dirs[e];
    float om  = 1.0f - q;
    float mag = kc * q * om * om * om;
    float gx = -d.x * mag;
    float gy = -d.y * mag;
    float g2 = gx * gx + gy * gy;
    float4 ja = pre2[2 * (size_t)j];      // {p, r, aa, aa2m}
    float4 jb = pre2[2 * (size_t)j + 1];
    float4 ia = pre2[2 * (size_t)i];
    float4 ib = pre2[2 * (size_t)i + 1];
    float aaj = ja.z;
    float m   = ja.y * aaj;
    float pp  = -m * (ia.x + ja.x);
    float vdotg = (ib.x - jb.x) * gx + (ib.y - jb.y) * gy;
    float adotg = (ib.z - jb.z) * gx + (ib.w - jb.w) * gy;
    float* base = acc + (size_t)i * 8;
    atomicAdd(base + 0, aaj * gx);
    atomicAdd(base + 1, aaj * gy);
    atomicAdd(base + 2, ja.w * g2);
    atomicAdd(base + 3, pp * gx);
    atomicAdd(base + 4, pp * gy);
    atomicAdd(base + 5, -dt * aaj * vdotg);
    atomicAdd(base + 6, dt * dt * aaj * adotg);
}

__global__ __launch_bounds__(256) void fin_kernel(
    const float* __restrict__ area,
    const float* __restrict__ actualArea,
    const float* __restrict__ restDensity,
    const float* __restrict__ dtp,
    const float* __restrict__ data, int mode, int nslice,
    float* __restrict__ out, int n) {
    int t = blockIdx.x * blockDim.x + threadIdx.x;
    if (t >= n) return;
    float s0 = 0, s1 = 0, s2 = 0, s3 = 0, s4 = 0, s5 = 0, s6 = 0;
    if (mode == 0) {
        const float* base = data + ((size_t)(t >> PB_SHIFT) * SLICES) * (PB * 7)
                                 + (size_t)(t & (PB - 1)) * 7;
        for (int s = 0; s < nslice; ++s) {
            const float* p = base + (size_t)s * (PB * 7);
            s0 += p[0]; s1 += p[1]; s2 += p[2]; s3 += p[3];
            s4 += p[4]; s5 += p[5]; s6 += p[6];
        }
    } else {
        const float* a = data + (size_t)t * 8;
        s0 = a[0]; s1 = a[1]; s2 = a[2]; s3 = a[3];
        s4 = a[4]; s5 = a[5]; s6 = a[6];
    }
    float dt   = dtp[0];
    float fac  = -dt * dt * actualArea[t];
    float mass = area[t] * restDensity[t];
    float alpha = fac / mass * (s0 * s0 + s1 * s1) + fac * s2;
    float* o = out + (size_t)t * 5;
    o[0] = alpha;
    o[1] = s3;
    o[2] = s4;
    o[3] = s5;
    o[4] = s6;
}

extern "C" void kernel_launch(void* const* d_in, const int* in_sizes, int n_in,
                              void* d_out, int out_size, void* d_ws, size_t ws_size,
                              hipStream_t stream) {
    const float* area        = (const float*)d_in[0];
    const float* actualArea  = (const float*)d_in[1];
    const float* restDensity = (const float*)d_in[2];
    const float* density     = (const float*)d_in[3];
    const float* pressure2   = (const float*)d_in[4];
    const float2* vel        = (const float2*)d_in[5];
    const float2* accel      = (const float2*)d_in[6];
    const float* rad         = (const float*)d_in[7];
    const float2* dirs       = (const float2*)d_in[8];
    const int*   nbr         = (const int*)d_in[9];
    const float* supp        = (const float*)d_in[10];
    const float* dtp         = (const float*)d_in[11];
    float* out = (float*)d_out;

    int N = in_sizes[0];
    int E = in_sizes[7];
    int nb = (N + PB - 1) >> PB_SHIFT;   // 512 for N=262144

    size_t sz_cur   = (size_t)nb * NR * CSTRIDE * 8 * sizeof(int);
    size_t off_pre  = align256(sz_cur);
    size_t sz_pre   = (size_t)N * 8 * sizeof(float);
    size_t off_part = align256(off_pre + sz_pre);
    size_t sz_part  = (size_t)nb * SLICES * PB * 7 * sizeof(float);
    size_t off_pay  = align256(off_part + sz_part);

    int* cursor     = (int*)d_ws;
    float4* pre2    = (float4*)((char*)d_ws + off_pre);
    float* partials = (float*)((char*)d_ws + off_part);

    // pick chunking so payload fits (12B records, NR regions per bucket)
    int nchunk = 0, cap = 0;
    if (nb <= 512 && ws_size > off_pay) {
        for (int c = 1; c <= 8; c *= 2) {
            long long Ec = (E + c - 1) / c;
            double mean = (double)Ec / ((double)nb * NR);
            long long need = (long long)(mean + 8.0 * sqrt(mean) + 64.0);
            need = (need + 63) & ~63ll;
            if (off_pay + (size_t)nb * NR * need * 12 <= ws_size) {
                nchunk = c; cap = (int)need; break;
            }
        }
    }

    int bs = 256;
    int grid_n = (N + bs - 1) / bs;
    if (nchunk > 0) {
        unsigned int* pay32 = (unsigned int*)((char*)d_ws + off_pay);
        int ncursor = nb * NR * CSTRIDE * nchunk;
        pre_kernel<<<grid_n, bs, 0, stream>>>(
            area, actualArea, restDensity, density, pressure2, vel, accel,
            pre2, cursor, ncursor, (float*)nullptr, 0, N);
        int Ec  = (E + nchunk - 1) / nchunk;
        for (int c = 0; c < nchunk; ++c) {
            int es = c * Ec;
            int ee = es + Ec; if (ee > E) ee = E;
            if (es >= ee) break;
            int* curC = cursor + (size_t)c * nb * NR * CSTRIDE;
            int nblk = (ee - es + BIN_EDGES - 1) / BIN_EDGES;
            bin_kernel<<<nblk, bs, 0, stream>>>(
                nbr, rad, dirs, supp, curC, pay32, cap, nb, es, ee, E);
            reduce_kernel<<<nb * NR, bs, 0, stream>>>(
                pay32, curC, cap, pre2, dtp, partials, (c > 0) ? 1 : 0, N);
        }
        fin_kernel<<<grid_n, bs, 0, stream>>>(
            area, actualArea, restDensity, dtp, partials, 0, SLICES, out, N);
    } else {
        float* acc = partials;  // [N,8] at off_part
        pre_kernel<<<grid_n, bs, 0, stream>>>(
            area, actualArea, restDensity, density, pressure2, vel, accel,
            pre2, cursor, 0, acc, N * 8, N);
        edge_kernel<<<(E + bs - 1) / bs, bs, 0, stream>>>(
            nbr, rad, dirs, pre2, supp, dtp, acc, E);
        fin_kernel<<<grid_n, bs, 0, stream>>>(
            area, actualArea, restDensity, dtp, acc, 1, 0, out, N);
    }
}

// Round 5
// 389.355 us; speedup vs baseline: 1.2361x; 1.0219x over previous
//
#include <hip/hip_runtime.h>
#include <math.h>

// -----------------------------------------------------------------------------
// DFSPH divergence-solve, block-aggregated binning + sort-based reduce.
//   pre:    per-particle 32B {p, r=m/aa, aa, aa^2/m | vx,vy,ax,ay}; zero cursors.
//   bin:    2048 edges/block (64 VGPR), PURE STREAM. Payload split into NR=8
//           pseudo-XCD regions keyed by blockIdx&7 (adjacent cursor claims land
//           on the same XCD's L2 so partial 64B sectors merge: WRITE 224->167MB
//           measured r3). 12B record {jli=(j<<9)|li, gx, gy}. LDS counting sort
//           per block; writeout = 1 ds_read_b128 + 1 global dwordx3 per record.
//   reduce: nb*4 blocks; each handles regions {s, s+4} serially (halves partials
//           traffic + fewer blocks' prologues). Register double-buffered payload
//           loads (NONTEMPORAL via ext_vector v4f: read-once stream must not
//           evict pre2 gather lines from L2 -- r3 showed 270MB of gather misses
//           on the 8MB table). Counting sort per TILE=1024 into 6 SoA b32
//           arrays {C0,C1,C2,rc,vg,ag} (dt/dt^2 deferred to epilogue) -> LDS
//           30KB -> 5 blocks/CU (was 4). Gather = contiguous per-particle
//           segments, pure register accumulate.
//   fin:    partials padded to 8 floats -> 2x v4f nt loads per slice, 4 slices
//           (was 56 stride-28B scalar loads over 8 slices).
// Fallback (tiny ws): direct global float atomics.
// -----------------------------------------------------------------------------

#define PB        512
#define PB_SHIFT  9
#define NR        8       // bin payload regions (pseudo-XCD via blockIdx&7)
#define NSLICE    4       // partials slices (reduce block covers 2 regions)
#define CSTRIDE   16      // ints per cursor -> 64B, one cacheline each
#define BIN_EDGES 2048
#define TILE      1024    // records per reduce sort round

typedef float v2f __attribute__((ext_vector_type(2)));
typedef float v4f __attribute__((ext_vector_type(4)));

// LDS-only barrier: orders DS ops across the block WITHOUT draining vmcnt,
// so global loads/stores stay in flight across phases.
__device__ __forceinline__ void ldsbar() {
    asm volatile("s_waitcnt lgkmcnt(0)" ::: "memory");
    __builtin_amdgcn_s_barrier();
    asm volatile("" ::: "memory");
}

static inline size_t align256(size_t x) { return (x + 255) & ~(size_t)255; }

__global__ __launch_bounds__(256) void pre_kernel(
    const float*  __restrict__ area,
    const float*  __restrict__ actualArea,
    const float*  __restrict__ restDensity,
    const float*  __restrict__ density,
    const float*  __restrict__ pressure2,
    const float2* __restrict__ vel,
    const float2* __restrict__ accel,
    float4* __restrict__ pre2,
    int*    __restrict__ cursor, int ncursor,
    float*  __restrict__ accz, int nacc,
    int n) {
    int t = blockIdx.x * blockDim.x + threadIdx.x;
    int stride = gridDim.x * blockDim.x;
    for (int k = t; k < ncursor; k += stride) cursor[k] = 0;
    for (int k = t; k < nacc; k += stride) accz[k] = 0.f;
    if (t >= n) return;
    float m  = area[t] * restDensity[t];
    float dr = density[t] * restDensity[t];
    float p  = pressure2[t] / (dr * dr);
    float aa = actualArea[t];
    float2 v  = vel[t];
    float2 ac = accel[t];
    pre2[2 * (size_t)t]     = make_float4(p, m / aa, aa, aa * aa / m);
    pre2[2 * (size_t)t + 1] = make_float4(v.x, v.y, ac.x, ac.y);
}

__global__ __launch_bounds__(256) void bin_kernel(
    const int*    __restrict__ nbr,
    const float*  __restrict__ rad,
    const float2* __restrict__ dirs,
    const float*  __restrict__ supp,
    int*          __restrict__ cursor,
    unsigned int* __restrict__ pay32,
    int cap, int nb, int estart, int eend, int E) {
    __shared__ float4 srec[BIN_EDGES];   // 32 KB sorted {jli,gx,gy,gd}
    __shared__ int lcount[512];          //  2 KB per-bucket counts
    __shared__ int lclaim[512];          //  2 KB claimed global record base
    __shared__ int lstart[512];          //  2 KB exclusive scan (LDS slot)
    int tid = threadIdx.x;
    int x   = blockIdx.x & (NR - 1);     // pseudo-XCD region
    for (int k = tid; k < 512; k += 256) lcount[k] = 0;
    ldsbar();
    int e0 = estart + blockIdx.x * BIN_EDGES + tid;

    // phase 1: stream 8 edges/thread into registers, rank per bucket
    int jj[8]; float qq[8]; v2f dd[8]; int pk[8];
#pragma unroll
    for (int k = 0; k < 8; ++k) {
        int e = e0 + k * 256;
        pk[k] = -1; jj[k] = 0; qq[k] = 0.f; dd[k] = (v2f){0.f, 0.f};
        if (e < eend) {
            jj[k] = __builtin_nontemporal_load(nbr + E + e);
            qq[k] = __builtin_nontemporal_load(rad + e);
            dd[k] = __builtin_nontemporal_load((const v2f*)dirs + e);
            int i = __builtin_nontemporal_load(nbr + e);
            int b = i >> PB_SHIFT;
            int r = atomicAdd(&lcount[b], 1);
            pk[k] = (b << 21) | ((i & (PB - 1)) << 12) | r;
        }
    }
    ldsbar();
    // waves 1-3: one cursor claim per (block,bucket) in region x;
    // wave 0: exclusive scan of counts (concurrent)
    if (tid >= 64) {
        for (int k = tid - 64; k < nb; k += 192) {
            int c = lcount[k];
            lclaim[k] = c ? atomicAdd(&cursor[(size_t)(k * NR + x) * CSTRIDE], c) : 0;
        }
    } else {
        int running = 0;
        for (int c = 0; c < 8; ++c) {
            int orig = lcount[c * 64 + tid];
            int v = orig;
#pragma unroll
            for (int off = 1; off < 64; off <<= 1) {
                int u = __shfl_up(v, off, 64);
                if (tid >= off) v += u;
            }
            lstart[c * 64 + tid] = running + v - orig;
            running += __shfl(v, 63, 64);
        }
    }
    ldsbar();

    float h  = supp[0];
    float kc = 20.0f * (7.0f / 3.14159265358979323846f) / (h * h * h);
    int cap3  = cap * 3;       // dwords per region
    int cap24 = cap * 3 * NR;  // dwords per bucket

    // phase 2: compute gradient, scatter 16B record into bucket-sorted LDS
#pragma unroll
    for (int k = 0; k < 8; ++k) {
        if (pk[k] < 0) continue;
        int b  = pk[k] >> 21;
        int li = (pk[k] >> 12) & (PB - 1);
        int r  = pk[k] & 2047;
        float  q = qq[k];
        v2f    d = dd[k];
        float om  = 1.0f - q;
        float mag = kc * q * om * om * om;
        float gx = -d.x * mag;
        float gy = -d.y * mag;
        int g  = lclaim[b] + r;
        int gd = (g < cap) ? (b * cap24 + x * cap3 + g * 3) : -1;  // 8-sigma drop
        srec[lstart[b] + r] = make_float4(
            __int_as_float((jj[k] << PB_SHIFT) | li), gx, gy, __int_as_float(gd));
    }
    ldsbar();
    // writeout: 1 b128 LDS read + 1 dwordx3 store per record; bucket runs are
    // contiguous; same-region neighbor claims share an L2 -> sectors merge.
    int total = lstart[511] + lcount[511];
    for (int r = tid; r < total; r += 256) {
        float4 rec = srec[r];
        int gd = __float_as_int(rec.w);
        if (gd >= 0) {
            uint3 w = make_uint3(__float_as_uint(rec.x), __float_as_uint(rec.y),
                                 __float_as_uint(rec.z));
            *(uint3*)(pay32 + gd) = w;
        }
    }
}

__global__ __launch_bounds__(256) void reduce_kernel(
    const unsigned int* __restrict__ pay32,
    const int*    __restrict__ cursor, int cap,
    const float4* __restrict__ pre2,
    const float*  __restrict__ dtp,
    float*        __restrict__ partials,
    int accum, int n) {
    __shared__ float s7[6][TILE];        // 24 KB SoA expanded records
    __shared__ int   lhist[PB];          //  2 KB counts
    __shared__ int   lofs[PB];           //  2 KB offsets -> cursors
    __shared__ float ptab[PB];           //  2 KB per-particle p
    int b   = blockIdx.x >> 2;
    int sb  = blockIdx.x & (NSLICE - 1);
    int tid = threadIdx.x;

    int p0 = (b << PB_SHIFT) + tid;
    int p1 = p0 + 256;
    float pi0 = (p0 < n) ? pre2[2 * (size_t)p0].x : 0.f;
    float pi1 = (p1 < n) ? pre2[2 * (size_t)p1].x : 0.f;
    ptab[tid] = pi0; ptab[tid + 256] = pi1;
    float a0[7] = {0.f, 0.f, 0.f, 0.f, 0.f, 0.f, 0.f};
    float a1[7] = {0.f, 0.f, 0.f, 0.f, 0.f, 0.f, 0.f};

    int r0 = tid * 4;                    // this thread's 4 records per tile
    for (int rg = 0; rg < 2; ++rg) {
        int s = sb + rg * NSLICE;        // regions sb and sb+4
        int cnt = cursor[(size_t)(b * NR + s) * CSTRIDE];
        if (cnt > cap) cnt = cap;
        size_t RB = (size_t)(b * NR + s) * cap * 3;  // dword base of region

        v4f c0v, c1v, c2v, n0v, n1v, n2v;
        if (cnt > 0) {
            int rb = r0;
            int rc_ = (rb + 4 <= cap) ? rb : (cap - 4);
            const v4f* g = (const v4f*)(pay32 + RB + (size_t)rc_ * 3);
            c0v = __builtin_nontemporal_load(g);
            c1v = __builtin_nontemporal_load(g + 1);
            c2v = __builtin_nontemporal_load(g + 2);
        }
        for (int T = 0; T < cnt; T += TILE) {
            lhist[tid] = 0; lhist[tid + 256] = 0;
            // issue next tile's nt loads (in flight across whole pipeline)
            if (T + TILE < cnt) {
                int rb = T + TILE + r0;
                int rc_ = (rb + 4 <= cap) ? rb : (cap - 4);
                const v4f* g = (const v4f*)(pay32 + RB + (size_t)rc_ * 3);
                n0v = __builtin_nontemporal_load(g);
                n1v = __builtin_nontemporal_load(g + 1);
                n2v = __builtin_nontemporal_load(g + 2);
            }
            // decode 4 records; issue pre2[j] gathers EARLY (normal loads: L2)
            int rb = T + r0;
            bool v0 = rb < cnt, v1 = rb + 1 < cnt, v2 = rb + 2 < cnt, v3 = rb + 3 < cnt;
            int jli0 = __float_as_int(c0v.x); float gx0 = c0v.y, gy0 = c0v.z;
            int jli1 = __float_as_int(c0v.w); float gx1 = c1v.x, gy1 = c1v.y;
            int jli2 = __float_as_int(c1v.z); float gx2 = c1v.w, gy2 = c2v.x;
            int jli3 = __float_as_int(c2v.y); float gx3 = c2v.z, gy3 = c2v.w;
            int li0 = jli0 & (PB - 1), li1 = jli1 & (PB - 1);
            int li2 = jli2 & (PB - 1), li3 = jli3 & (PB - 1);
            size_t j0 = v0 ? (size_t)(jli0 >> PB_SHIFT) : 0;
            size_t j1 = v1 ? (size_t)(jli1 >> PB_SHIFT) : 0;
            size_t j2 = v2 ? (size_t)(jli2 >> PB_SHIFT) : 0;
            size_t j3 = v3 ? (size_t)(jli3 >> PB_SHIFT) : 0;
            float4 ja0 = pre2[2 * j0], jb0 = pre2[2 * j0 + 1];
            float4 ja1 = pre2[2 * j1], jb1 = pre2[2 * j1 + 1];
            float4 ja2 = pre2[2 * j2], jb2 = pre2[2 * j2 + 1];
            float4 ja3 = pre2[2 * j3], jb3 = pre2[2 * j3 + 1];
            ldsbar();          // hist zeros + ptab visible
            if (v0) atomicAdd(&lhist[li0], 1);
            if (v1) atomicAdd(&lhist[li1], 1);
            if (v2) atomicAdd(&lhist[li2], 1);
            if (v3) atomicAdd(&lhist[li3], 1);
            ldsbar();
            // exclusive prefix scan of 512 counts by wave 0
            if (tid < 64) {
                int running = 0;
                for (int c = 0; c < 8; ++c) {
                    int orig = lhist[c * 64 + tid];
                    int v = orig;
#pragma unroll
                    for (int off = 1; off < 64; off <<= 1) {
                        int u = __shfl_up(v, off, 64);
                        if (tid >= off) v += u;
                    }
                    lofs[c * 64 + tid] = running + v - orig;
                    running += __shfl(v, 63, 64);
                }
            }
            ldsbar();
            // scatter: expand into 6 SoA b32 arrays in particle-sorted order
#define SCAT(vv, li, jaa, jbb, gxx, gyy)                                     \
            if (vv) {                                                        \
                int sl = atomicAdd(&lofs[li], 1);                            \
                float C0 = jaa.z * gxx;                                      \
                float C1 = jaa.z * gyy;                                      \
                s7[0][sl] = C0;                                              \
                s7[1][sl] = C1;                                              \
                s7[2][sl] = jaa.w * (gxx * gxx + gyy * gyy);                 \
                s7[3][sl] = -(ptab[li] + jaa.x) * jaa.y;                     \
                s7[4][sl] = jbb.x * C0 + jbb.y * C1;                         \
                s7[5][sl] = jbb.z * C0 + jbb.w * C1;                         \
            }
            SCAT(v0, li0, ja0, jb0, gx0, gy0)
            SCAT(v1, li1, ja1, jb1, gx1, gy1)
            SCAT(v2, li2, ja2, jb2, gx2, gy2)
            SCAT(v3, li3, ja3, jb3, gx3, gy3)
#undef SCAT
            ldsbar();
            // gather: contiguous segment per particle, pure-sum b32 reads
            {
                int e0 = lofs[tid], h0 = lhist[tid];
                for (int r = e0 - h0; r < e0; ++r) {
                    float C0 = s7[0][r], C1 = s7[1][r], rc = s7[3][r];
                    a0[0] += C0; a0[1] += C1; a0[2] += s7[2][r];
                    a0[3] += rc * C0; a0[4] += rc * C1;
                    a0[5] += s7[4][r]; a0[6] += s7[5][r];
                }
                int e1 = lofs[tid + 256], h1 = lhist[tid + 256];
                for (int r = e1 - h1; r < e1; ++r) {
                    float C0 = s7[0][r], C1 = s7[1][r], rc = s7[3][r];
                    a1[0] += C0; a1[1] += C1; a1[2] += s7[2][r];
                    a1[3] += rc * C0; a1[4] += rc * C1;
                    a1[5] += s7[4][r]; a1[6] += s7[5][r];
                }
            }
            ldsbar();          // gather done before next tile zeroes lhist
            c0v = n0v; c1v = n1v; c2v = n2v;
        }
    }

    // epilogue: dt scaling + linear i-side corrections; 8-float padded record
    float dt  = dtp[0];
    float dt2 = dt * dt;
    v4f* dst = (v4f*)(partials + ((size_t)b * NSLICE + sb) * (PB * 8));
    {
        float4 va = (p0 < n) ? pre2[2 * (size_t)p0 + 1]
                             : make_float4(0.f, 0.f, 0.f, 0.f);
        float src = dt  * (a0[5] - (va.x * a0[0] + va.y * a0[1]));
        float ker = dt2 * ((va.z * a0[0] + va.w * a0[1]) - a0[6]);
        v4f w0 = {a0[0], a0[1], a0[2], a0[3]};
        v4f w1 = {a0[4], src, ker, 0.f};
        v4f* d = dst + (size_t)tid * 2;
        if (accum) {
            v4f o0 = d[0], o1 = d[1];
            d[0] = w0 + o0; d[1] = w1 + o1;
        } else {
            __builtin_nontemporal_store(w0, d);
            __builtin_nontemporal_store(w1, d + 1);
        }
    }
    {
        float4 va = (p1 < n) ? pre2[2 * (size_t)p1 + 1]
                             : make_float4(0.f, 0.f, 0.f, 0.f);
        float src = dt  * (a1[5] - (va.x * a1[0] + va.y * a1[1]));
        float ker = dt2 * ((va.z * a1[0] + va.w * a1[1]) - a1[6]);
        v4f w0 = {a1[0], a1[1], a1[2], a1[3]};
        v4f w1 = {a1[4], src, ker, 0.f};
        v4f* d = dst + (size_t)(tid + 256) * 2;
        if (accum) {
            v4f o0 = d[0], o1 = d[1];
            d[0] = w0 + o0; d[1] = w1 + o1;
        } else {
            __builtin_nontemporal_store(w0, d);
            __builtin_nontemporal_store(w1, d + 1);
        }
    }
}

// ---- fallback: direct global float atomics ----
__global__ void edge_kernel(const int* __restrict__ nbr,
                            const float* __restrict__ rad,
                            const float2* __restrict__ dirs,
                            const float4* __restrict__ pre2,
                            const float* __restrict__ supp,
                            const float* __restrict__ dtp,
                            float* __restrict__ acc, int E) {
    int e = blockIdx.x * blockDim.x + threadIdx.x;
    if (e >= E) return;
    float h = supp[0], dt = dtp[0];
    float kc = 20.0f * (7.0f / 3.14159265358979323846f) / (h * h * h);
    int i = nbr[e];
    int j = nbr[E + e];
    float  q = rad[e];
    float2 d = dirs[e];
    float om  = 1.0f - q;
    float mag = kc * q * om * om * om;
    float gx = -d.x * mag;
    float gy = -d.y * mag;
    float g2 = gx * gx + gy * gy;
    float4 ja = pre2[2 * (size_t)j];      // {p, r, aa, aa2m}
    float4 jb = pre2[2 * (size_t)j + 1];
    float4 ia = pre2[2 * (size_t)i];
    float4 ib = pre2[2 * (size_t)i + 1];
    float aaj = ja.z;
    float m   = ja.y * aaj;
    float pp  = -m * (ia.x + ja.x);
    float vdotg = (ib.x - jb.x) * gx + (ib.y - jb.y) * gy;
    float adotg = (ib.z - jb.z) * gx + (ib.w - jb.w) * gy;
    float* base = acc + (size_t)i * 8;
    atomicAdd(base + 0, aaj * gx);
    atomicAdd(base + 1, aaj * gy);
    atomicAdd(base + 2, ja.w * g2);
    atomicAdd(base + 3, pp * gx);
    atomicAdd(base + 4, pp * gy);
    atomicAdd(base + 5, -dt * aaj * vdotg);
    atomicAdd(base + 6, dt * dt * aaj * adotg);
}

__global__ __launch_bounds__(256) void fin_kernel(
    const float* __restrict__ area,
    const float* __restrict__ actualArea,
    const float* __restrict__ restDensity,
    const float* __restrict__ dtp,
    const float* __restrict__ data, int mode, int nslice,
    float* __restrict__ out, int n) {
    int t = blockIdx.x * blockDim.x + threadIdx.x;
    if (t >= n) return;
    float s0 = 0, s1 = 0, s2 = 0, s3 = 0, s4 = 0, s5 = 0, s6 = 0;
    if (mode == 0) {
        const v4f* base = (const v4f*)data
            + ((size_t)(t >> PB_SHIFT) * NSLICE) * (PB * 2)
            + (size_t)(t & (PB - 1)) * 2;
        for (int s = 0; s < nslice; ++s) {
            v4f q0 = __builtin_nontemporal_load(base + (size_t)s * (PB * 2));
            v4f q1 = __builtin_nontemporal_load(base + (size_t)s * (PB * 2) + 1);
            s0 += q0.x; s1 += q0.y; s2 += q0.z; s3 += q0.w;
            s4 += q1.x; s5 += q1.y; s6 += q1.z;
        }
    } else {
        const float* a = data + (size_t)t * 8;
        s0 = a[0]; s1 = a[1]; s2 = a[2]; s3 = a[3];
        s4 = a[4]; s5 = a[5]; s6 = a[6];
    }
    float dt   = dtp[0];
    float fac  = -dt * dt * actualArea[t];
    float mass = area[t] * restDensity[t];
    float alpha = fac / mass * (s0 * s0 + s1 * s1) + fac * s2;
    float* o = out + (size_t)t * 5;
    o[0] = alpha;
    o[1] = s3;
    o[2] = s4;
    o[3] = s5;
    o[4] = s6;
}

extern "C" void kernel_launch(void* const* d_in, const int* in_sizes, int n_in,
                              void* d_out, int out_size, void* d_ws, size_t ws_size,
                              hipStream_t stream) {
    const float* area        = (const float*)d_in[0];
    const float* actualArea  = (const float*)d_in[1];
    const float* restDensity = (const float*)d_in[2];
    const float* density     = (const float*)d_in[3];
    const float* pressure2   = (const float*)d_in[4];
    const float2* vel        = (const float2*)d_in[5];
    const float2* accel      = (const float2*)d_in[6];
    const float* rad         = (const float*)d_in[7];
    const float2* dirs       = (const float2*)d_in[8];
    const int*   nbr         = (const int*)d_in[9];
    const float* supp        = (const float*)d_in[10];
    const float* dtp         = (const float*)d_in[11];
    float* out = (float*)d_out;

    int N = in_sizes[0];
    int E = in_sizes[7];
    int nb = (N + PB - 1) >> PB_SHIFT;   // 512 for N=262144

    size_t sz_cur   = (size_t)nb * NR * CSTRIDE * 8 * sizeof(int);
    size_t off_pre  = align256(sz_cur);
    size_t sz_pre   = (size_t)N * 8 * sizeof(float);
    size_t off_part = align256(off_pre + sz_pre);
    size_t sz_partA = (size_t)nb * NSLICE * PB * 8 * sizeof(float);
    size_t sz_partB = (size_t)N * 8 * sizeof(float);   // fallback acc layout
    size_t sz_part  = sz_partA > sz_partB ? sz_partA : sz_partB;
    size_t off_pay  = align256(off_part + sz_part);

    int* cursor     = (int*)d_ws;
    float4* pre2    = (float4*)((char*)d_ws + off_pre);
    float* partials = (float*)((char*)d_ws + off_part);

    // pick chunking so payload fits (12B records, NR regions per bucket)
    int nchunk = 0, cap = 0;
    if (nb <= 512 && ws_size > off_pay) {
        for (int c = 1; c <= 8; c *= 2) {
            long long Ec = (E + c - 1) / c;
            double mean = (double)Ec / ((double)nb * NR);
            long long need = (long long)(mean + 8.0 * sqrt(mean) + 64.0);
            need = (need + 63) & ~63ll;
            if (off_pay + (size_t)nb * NR * need * 12 <= ws_size) {
                nchunk = c; cap = (int)need; break;
            }
        }
    }

    int bs = 256;
    int grid_n = (N + bs - 1) / bs;
    if (nchunk > 0) {
        unsigned int* pay32 = (unsigned int*)((char*)d_ws + off_pay);
        int ncursor = nb * NR * CSTRIDE * nchunk;
        pre_kernel<<<grid_n, bs, 0, stream>>>(
            area, actualArea, restDensity, density, pressure2, vel, accel,
            pre2, cursor, ncursor, (float*)nullptr, 0, N);
        int Ec  = (E + nchunk - 1) / nchunk;
        for (int c = 0; c < nchunk; ++c) {
            int es = c * Ec;
            int ee = es + Ec; if (ee > E) ee = E;
            if (es >= ee) break;
            int* curC = cursor + (size_t)c * nb * NR * CSTRIDE;
            int nblk = (ee - es + BIN_EDGES - 1) / BIN_EDGES;
            bin_kernel<<<nblk, bs, 0, stream>>>(
                nbr, rad, dirs, supp, curC, pay32, cap, nb, es, ee, E);
            reduce_kernel<<<nb * NSLICE, bs, 0, stream>>>(
                pay32, curC, cap, pre2, dtp, partials, (c > 0) ? 1 : 0, N);
        }
        fin_kernel<<<grid_n, bs, 0, stream>>>(
            area, actualArea, restDensity, dtp, partials, 0, NSLICE, out, N);
    } else {
        float* acc = partials;  // [N,8] at off_part
        pre_kernel<<<grid_n, bs, 0, stream>>>(
            area, actualArea, restDensity, density, pressure2, vel, accel,
            pre2, cursor, 0, acc, N * 8, N);
        edge_kernel<<<(E + bs - 1) / bs, bs, 0, stream>>>(
            nbr, rad, dirs, pre2, supp, dtp, acc, E);
        fin_kernel<<<grid_n, bs, 0, stream>>>(
            area, actualArea, restDensity, dtp, acc, 1, 0, out, N);
    }
}